// Round 5
// baseline (481.510 us; speedup 1.0000x reference)
//
#include <hip/hip_runtime.h>

#define BATCH 16
#define SEQ   4096
#define HEADS 16
#define EMB   64
#define SS    64      // s = sqrt(SEQ)
#define NW    127     // 2*s - 1
#define PLANE (HEADS * EMB)                  // 1024 floats per seq position

#define US_ELEMS    (BATCH * SS * PLANE)     // 1M floats  = 4 MB
#define VPART_ELEMS (BATCH * 8 * SS * PLANE) // 8M floats  = 32 MB
// ws layout: v_part (32MB) | u_s (4MB) | rxv (4MB) | rxu (4MB)
#define WS_NEEDED ((size_t)(VPART_ELEMS + 3 * US_ELEMS) * sizeof(float))

// ---------------------------------------------------------------------------
// Kernel 1: fully-contiguous float4 pass over v. No atomics, no memset.
// Grid: 512 = b(16) x q(seq-eighth,8) x cq(col-quarter,4); 256 thr (4 waves).
// Block reads v[b, q*512:(q+1)*512, cols cq*256:+256]; every wave load is
// 64 lanes x 16B = 1KB contiguous. 2 blocks/CU -> 8 waves/CU.
// Wave w owns j with j%4==w: the 16 vacc registers are a COMPLETE disjoint
// slice of this block's v_s partial -> plain stores, static indexing.
//   u_s[b][q*8+il][cols]   : complete rows (one LDS merge across 4 waves)
//   v_part[b][q][j][cols]  : per-eighth partial (sum over 8 i's)
// ---------------------------------------------------------------------------
__global__ __launch_bounds__(256) void sums_kernel(
    const float4* __restrict__ v4, float4* __restrict__ vpart4,
    float4* __restrict__ us4)
{
    __shared__ float4 u_lds[4][8][64];    // [w][il][c4] : 32 KB

    const int blk = blockIdx.x;
    const int b   = blk >> 5;             // 16
    const int q   = (blk >> 2) & 7;       // 8
    const int cq  = blk & 3;              // 4
    const int tid = threadIdx.x;
    const int w   = tid >> 6;             // wave 0..3  == j mod 4
    const int c4  = tid & 63;             // float4 col within quarter

    const float4* base = v4 + (((size_t)(b * SEQ + q * 512)) << 8)
                            + (cq << 6) + c4;

    float4 vacc[16];
    #pragma unroll
    for (int m = 0; m < 16; ++m) vacc[m] = make_float4(0.f, 0.f, 0.f, 0.f);

    for (int il = 0; il < 8; ++il) {      // local i within eighth
        float4 uacc = make_float4(0.f, 0.f, 0.f, 0.f);
        #pragma unroll
        for (int m = 0; m < 16; ++m) {    // j = w + 4m  (static vacc index)
            const float4 x = base[(size_t)((il << 6) + w + (m << 2)) << 8];
            uacc.x += x.x; uacc.y += x.y; uacc.z += x.z; uacc.w += x.w;
            vacc[m].x += x.x; vacc[m].y += x.y;
            vacc[m].z += x.z; vacc[m].w += x.w;
        }
        u_lds[w][il][c4] = uacc;
    }
    __syncthreads();

    // u_s: reduce the 4 wave-partials, store complete rows
    {
        int s = tid;
        #pragma unroll
        for (int r = 0; r < 2; ++r, s += 256) {   // 512 slots / 256 threads
            const int il = s >> 6, c = s & 63;
            float4 a = u_lds[0][il][c];
            #pragma unroll
            for (int ww = 1; ww < 4; ++ww) {
                const float4 x = u_lds[ww][il][c];
                a.x += x.x; a.y += x.y; a.z += x.z; a.w += x.w;
            }
            us4[((size_t)((b << 6) + (q << 3) + il) << 8) + (cq << 6) + c] = a;
        }
    }

    // v_part: disjoint plain stores (wave w owns j = w+4m)
    #pragma unroll
    for (int m = 0; m < 16; ++m) {
        const int j = w + (m << 2);
        vpart4[((size_t)((((b << 3) + q) << 6) + j) << 8) + (cq << 6) + c4]
            = vacc[m];
    }
}

// ---------------------------------------------------------------------------
// Kernel 2: merge 8 v_s partials + circular-Toeplitz matvec -> RxV, RxU.
// RxV[b][t][h][e] = sum_j w[h][(t-j+64)%127] * v_s[b][j][h][e]; same for U.
// Grid: B*H = 256 blocks, 256 threads (4 waves x 16 t-values), lane = e.
// ---------------------------------------------------------------------------
__global__ __launch_bounds__(256) void conv_kernel(
    const float* __restrict__ w, const float4* __restrict__ vpart4,
    const float4* __restrict__ us4, float* __restrict__ rxv,
    float* __restrict__ rxu)
{
    __shared__ float wtab[NW];
    __shared__ float vsl[SS][SS];
    __shared__ float usl[SS][SS];

    const int bh   = blockIdx.x;
    const int b    = bh >> 4;
    const int h    = bh & (HEADS - 1);
    const int tid  = threadIdx.x;
    const int wave = tid >> 6;
    const int lane = tid & 63;

    if (tid < NW) wtab[tid] = w[h * NW + tid];

    // merge the 8 q-partials of v_s for this (b,h) slice; stage u_s
    for (int s = tid; s < SS * 16; s += 256) {    // s = j*16 + e4
        const int j = s >> 4, e4 = s & 15;
        float4 acc = make_float4(0.f, 0.f, 0.f, 0.f);
        #pragma unroll
        for (int q = 0; q < 8; ++q) {
            const float4 x =
                vpart4[((size_t)((((b << 3) + q) << 6) + j) << 8) + (h << 4) + e4];
            acc.x += x.x; acc.y += x.y; acc.z += x.z; acc.w += x.w;
        }
        *(float4*)&vsl[j][e4 << 2] = acc;
        *(float4*)&usl[j][e4 << 2] =
            us4[((size_t)((b << 6) + j) << 8) + (h << 4) + e4];
    }
    __syncthreads();

    const int t0 = wave * 16;
    float accv[16], accu[16];
    #pragma unroll
    for (int tt = 0; tt < 16; ++tt) { accv[tt] = 0.0f; accu[tt] = 0.0f; }

    #pragma unroll
    for (int jb = 0; jb < 4; ++jb) {
        float wreg[31];
        #pragma unroll
        for (int d = 0; d < 31; ++d) {
            int idx = t0 - jb * 16 + 49 + d;   // in [1,127]
            if (idx >= NW) idx -= NW;
            wreg[d] = wtab[idx];
        }
        #pragma unroll
        for (int jj = 0; jj < 16; ++jj) {
            const float cv = vsl[jb * 16 + jj][lane];
            const float cu = usl[jb * 16 + jj][lane];
            #pragma unroll
            for (int tt = 0; tt < 16; ++tt) {
                const float cw = wreg[15 + tt - jj];   // = w[(t-j+64)%127]
                accv[tt] += cw * cv;
                accu[tt] += cw * cu;
            }
        }
    }

    #pragma unroll
    for (int tt = 0; tt < 16; ++tt) {
        const size_t o = ((size_t)(b * SS + t0 + tt) << 10) + (h << 6) + lane;
        rxv[o] = accv[tt];
        rxu[o] = accu[tt];
    }
}

// ---------------------------------------------------------------------------
// Kernel 3: expand (round-3-verified). out[b,i*64+j,h,e] = RxV[b][j][h][e]
// + RxU[b][i][h][e]. Grid: B*64 = 1024 blocks (4/CU), 256 thr, float4
// fully-contiguous 256 KB store stream per block; rx reads are L2/L3-warm.
// ---------------------------------------------------------------------------
__global__ __launch_bounds__(256) void expand_kernel(
    const float* __restrict__ rxv, const float* __restrict__ rxu,
    float* __restrict__ out)
{
    const int blk = blockIdx.x;        // b*64 + i
    const int b   = blk >> 6;
    const int tid = threadIdx.x;

    const float4 ru = *((const float4*)(rxu + ((size_t)blk << 10)) + tid);
    const float4* rvb = (const float4*)(rxv + ((size_t)b << 16));
    float4* ob = (float4*)(out + (((size_t)blk) << 16)) + tid;

    #pragma unroll 8
    for (int j = 0; j < SS; ++j) {
        float4 rv = rvb[(j << 8) + tid];
        float4 r;
        r.x = rv.x + ru.x; r.y = rv.y + ru.y;
        r.z = rv.z + ru.z; r.w = rv.w + ru.w;
        ob[(size_t)j << 8] = r;
    }
}

// ---------------------------------------------------------------------------
// Fallback (ws too small): round-0 fused kernel, verified at ~180 us.
// ---------------------------------------------------------------------------
__global__ __launch_bounds__(512) void pbv_kernel(const float* __restrict__ v,
                                                  const float* __restrict__ w,
                                                  float* __restrict__ out) {
    __shared__ float us [SS][SS];
    __shared__ float vsf[SS][SS];
    __shared__ float wtab[NW];

    const int bh   = blockIdx.x;
    const int b    = bh / HEADS;
    const int h    = bh % HEADS;
    const int tid  = threadIdx.x;
    const int wave = tid >> 6;
    const int lane = tid & 63;

    for (int idx = tid; idx < SS * SS; idx += 512) (&vsf[0][0])[idx] = 0.0f;
    if (tid < NW) wtab[tid] = w[h * NW + tid];
    __syncthreads();

    const float* vbase = v + ((size_t)b * SEQ * HEADS + h) * EMB + lane;
    float vsacc[SS];
    #pragma unroll
    for (int j = 0; j < SS; ++j) vsacc[j] = 0.0f;

    for (int ii = 0; ii < 8; ++ii) {
        const int i = wave * 8 + ii;
        const float* rowp = vbase + (size_t)i * SS * (HEADS * EMB);
        float uacc = 0.0f;
        #pragma unroll
        for (int j = 0; j < SS; ++j) {
            float val = rowp[(size_t)j * (HEADS * EMB)];
            uacc += val;
            vsacc[j] += val;
        }
        us[i][lane] = uacc;
    }
    #pragma unroll
    for (int j = 0; j < SS; ++j) atomicAdd(&vsf[j][lane], vsacc[j]);
    __syncthreads();

    float rv[8], ru[8];
    for (int tt = 0; tt < 8; ++tt) {
        const int t = wave * 8 + tt;
        float accv = 0.0f, accu = 0.0f;
        #pragma unroll
        for (int j = 0; j < SS; ++j) {
            int k = t - j + 64;
            if (k >= NW) k -= NW;
            const float c = wtab[k];
            accv += c * vsf[j][lane];
            accu += c * us [j][lane];
        }
        rv[tt] = accv;
        ru[tt] = accu;
    }
    __syncthreads();
    for (int tt = 0; tt < 8; ++tt) {
        const int t = wave * 8 + tt;
        vsf[t][lane] = rv[tt];
        us [t][lane] = ru[tt];
    }
    __syncthreads();

    float* obase = out + ((size_t)b * SEQ * HEADS + h) * EMB + lane;
    for (int ii = 0; ii < 8; ++ii) {
        const int i = wave * 8 + ii;
        const float ruv = us[i][lane];
        #pragma unroll
        for (int j = 0; j < SS; ++j) {
            obase[(size_t)(i * SS + j) * (HEADS * EMB)] = vsf[j][lane] + ruv;
        }
    }
}

// ---------------------------------------------------------------------------
// z_pb: zp[h][t] = s * sum_j o_[j] * w[h, (t-j+64)%127]
// out2[0, i*64+j, h] = zp[h][j] + zp[h][i].  Grid: 64 blocks (one per i).
// ---------------------------------------------------------------------------
__global__ __launch_bounds__(256) void zpb_kernel(const float* __restrict__ w,
                                                  const float* __restrict__ o_,
                                                  float* __restrict__ out2) {
    __shared__ float zp[HEADS][SS];
    __shared__ float osh[SS];
    __shared__ float wsh[HEADS * NW];

    const int tid = threadIdx.x;
    const int g   = blockIdx.x;   // i index

    if (tid < SS) osh[tid] = o_[tid];
    for (int idx = tid; idx < HEADS * NW; idx += 256) wsh[idx] = w[idx];
    __syncthreads();

    for (int idx = tid; idx < HEADS * SS; idx += 256) {
        const int h = idx / SS, t = idx % SS;
        float acc = 0.0f;
        #pragma unroll
        for (int j = 0; j < SS; ++j) {
            int k = t - j + 64;
            if (k >= NW) k -= NW;
            acc += osh[j] * wsh[h * NW + k];
        }
        zp[h][t] = acc * (float)SS;
    }
    __syncthreads();

    for (int idx = tid; idx < SS * HEADS; idx += 256) {
        const int tl = idx / HEADS, h = idx % HEADS;
        out2[(size_t)(g * SS + tl) * HEADS + h] = zp[h][tl] + zp[h][g];
    }
}

extern "C" void kernel_launch(void* const* d_in, const int* in_sizes, int n_in,
                              void* d_out, int out_size, void* d_ws, size_t ws_size,
                              hipStream_t stream) {
    const float* v  = (const float*)d_in[0];
    const float* w  = (const float*)d_in[1];
    const float* o_ = (const float*)d_in[2];
    float* out = (float*)d_out;

    if (ws_size >= WS_NEEDED) {
        float* vpart = (float*)d_ws;                 // 32 MB, disjoint writes
        float* us    = vpart + VPART_ELEMS;          // 4 MB
        float* rxv   = us    + US_ELEMS;             // 4 MB
        float* rxu   = rxv   + US_ELEMS;             // 4 MB

        sums_kernel<<<512, 256, 0, stream>>>(
            (const float4*)v, (float4*)vpart, (float4*)us);
        conv_kernel<<<BATCH * HEADS, 256, 0, stream>>>(
            w, (const float4*)vpart, (const float4*)us, rxv, rxu);
        expand_kernel<<<BATCH * SS, 256, 0, stream>>>(rxv, rxu, out);
    } else {
        pbv_kernel<<<BATCH * HEADS, 512, 0, stream>>>(v, w, out);
    }

    const size_t out1_elems = (size_t)BATCH * SEQ * HEADS * EMB;
    zpb_kernel<<<SS, 256, 0, stream>>>(w, o_, out + out1_elems);
}